// Round 1
// baseline (11046.013 us; speedup 1.0000x reference)
//
#include <hip/hip_runtime.h>

#define D 256

// ---------------------------------------------------------------------------
// Kernel 1: scatter-add.  One 64-lane wave per edge; each lane handles 4
// consecutive floats (float4 gather, 4x fp32 atomicAdd scatter).
// ---------------------------------------------------------------------------
__global__ __launch_bounds__(256) void scatter_kernel(
    const float* __restrict__ feature,
    const int* __restrict__ src,
    const int* __restrict__ dst,
    float* __restrict__ agg,
    int E)
{
    int edge = blockIdx.x * (blockDim.x >> 6) + (threadIdx.x >> 6);
    int lane = threadIdx.x & 63;
    if (edge >= E) return;

    int s = src[edge];
    int d = dst[edge];

    const float4 v = *reinterpret_cast<const float4*>(
        feature + (size_t)s * D + lane * 4);
    float* o = agg + (size_t)d * D + lane * 4;

    atomicAdd(o + 0, v.x);
    atomicAdd(o + 1, v.y);
    atomicAdd(o + 2, v.z);
    atomicAdd(o + 3, v.w);
}

// ---------------------------------------------------------------------------
// Kernel 2: in-place per-row Linear + ReLU.
// Block = 256 threads, BM = 32 nodes per block.
// Stage the 32 agg rows in LDS (32 KB); thread t computes output column t for
// all 32 nodes. sA[m][k] reads are wave-uniform broadcasts (conflict-free);
// W[k*D + t] reads are coalesced and L2-resident (W = 256 KB).
// h row i depends only on agg row i -> safe in-place after __syncthreads().
// ---------------------------------------------------------------------------
#define BM 32

__global__ __launch_bounds__(256) void linear_relu_kernel(
    float* __restrict__ h,              // in: agg, out: relu(agg@W + b)
    const float* __restrict__ W,        // [D][D] row-major
    const float* __restrict__ b,        // [D]
    int n_nodes)
{
    __shared__ float sA[BM][D];         // 32 KB

    const int node0 = blockIdx.x * BM;
    const int t = threadIdx.x;          // output column

    // stage 32 rows (each iteration: 256 threads load one row)
    for (int m = 0; m < BM; ++m) {
        int nd = node0 + m;
        sA[m][t] = (nd < n_nodes) ? h[(size_t)nd * D + t] : 0.0f;
    }
    __syncthreads();

    float acc[BM];
#pragma unroll
    for (int m = 0; m < BM; ++m) acc[m] = 0.0f;

    for (int k = 0; k < D; ++k) {
        float w = W[k * D + t];
#pragma unroll
        for (int m = 0; m < BM; ++m) acc[m] += sA[m][k] * w;
    }

    const float bias = b[t];
    for (int m = 0; m < BM; ++m) {
        int nd = node0 + m;
        if (nd < n_nodes) {
            float v = acc[m] + bias;
            h[(size_t)nd * D + t] = v > 0.0f ? v : 0.0f;
        }
    }
}

// ---------------------------------------------------------------------------
extern "C" void kernel_launch(void* const* d_in, const int* in_sizes, int n_in,
                              void* d_out, int out_size, void* d_ws, size_t ws_size,
                              hipStream_t stream)
{
    const float* feature = (const float*)d_in[0];
    const int*   src     = (const int*)d_in[1];
    const int*   dst     = (const int*)d_in[2];
    const float* W       = (const float*)d_in[3];
    const float* b       = (const float*)d_in[4];
    float*       out     = (float*)d_out;

    const int E = in_sizes[1];
    const int n_nodes = in_sizes[0] / D;

    // zero the accumulator (we accumulate directly into d_out)
    hipMemsetAsync(d_out, 0, (size_t)out_size * sizeof(float), stream);

    // scatter: 4 edges per 256-thread block
    {
        int edges_per_block = 256 / 64;
        int grid = (E + edges_per_block - 1) / edges_per_block;
        scatter_kernel<<<grid, 256, 0, stream>>>(feature, src, dst, out, E);
    }

    // in-place linear + relu
    {
        int grid = (n_nodes + BM - 1) / BM;
        linear_relu_kernel<<<grid, 256, 0, stream>>>(out, W, b, n_nodes);
    }
}

// Round 2
// 1506.356 us; speedup vs baseline: 7.3329x; 7.3329x over previous
//
#include <hip/hip_runtime.h>

#define D 256
#define N_FIXED 100000

// ---------------------------------------------------------------------------
// CSR-build path: counting sort of edges by dst, then per-node gather-reduce.
// ---------------------------------------------------------------------------

__global__ __launch_bounds__(256) void count_kernel(
    const int* __restrict__ dst, int* __restrict__ counts, int E)
{
    int i = blockIdx.x * blockDim.x + threadIdx.x;
    int stride = gridDim.x * blockDim.x;
    for (; i < E; i += stride) atomicAdd(&counts[dst[i]], 1);
}

// Single-block exclusive scan over N counts -> offsets (and a cursor copy).
__global__ __launch_bounds__(1024) void scan_kernel(
    const int* __restrict__ counts, int* __restrict__ offsets,
    int* __restrict__ cursor, int N)
{
    __shared__ int sm[1024];
    const int t = threadIdx.x;
    const int chunk = (N + 1023) / 1024;
    const int begin = min(t * chunk, N);
    const int end   = min(begin + chunk, N);

    int s = 0;
    for (int i = begin; i < end; ++i) s += counts[i];
    sm[t] = s;
    __syncthreads();

    // Hillis-Steele inclusive scan of per-thread sums
    for (int off = 1; off < 1024; off <<= 1) {
        int v = (t >= off) ? sm[t - off] : 0;
        __syncthreads();
        if (t >= off) sm[t] += v;
        __syncthreads();
    }

    int run = (t == 0) ? 0 : sm[t - 1];   // exclusive base
    for (int i = begin; i < end; ++i) {
        offsets[i] = run;
        cursor[i]  = run;
        run += counts[i];
    }
    if (end == N && begin < N) offsets[N] = run;
}

__global__ __launch_bounds__(256) void build_kernel(
    const int* __restrict__ src, const int* __restrict__ dst,
    int* __restrict__ cursor, int* __restrict__ csr_src, int E)
{
    int i = blockIdx.x * blockDim.x + threadIdx.x;
    int stride = gridDim.x * blockDim.x;
    for (; i < E; i += stride) {
        int d = dst[i];
        int p = atomicAdd(&cursor[d], 1);
        csr_src[p] = src[i];
    }
}

// One wave per node; lane owns 4 consecutive columns (float4).
__global__ __launch_bounds__(256) void aggregate_kernel(
    const float* __restrict__ feature,
    const int* __restrict__ csr_src,
    const int* __restrict__ offsets,
    const int* __restrict__ counts,
    float* __restrict__ agg, int N)
{
    int node = blockIdx.x * 4 + (threadIdx.x >> 6);
    int lane = threadIdx.x & 63;
    if (node >= N) return;

    const int beg = offsets[node];
    const int cnt = counts[node];

    float4 acc = make_float4(0.f, 0.f, 0.f, 0.f);
    int j = 0;
    // unroll-by-2 for a little more MLP
    for (; j + 1 < cnt; j += 2) {
        int s0 = csr_src[beg + j];
        int s1 = csr_src[beg + j + 1];
        float4 v0 = *reinterpret_cast<const float4*>(feature + (size_t)s0 * D + lane * 4);
        float4 v1 = *reinterpret_cast<const float4*>(feature + (size_t)s1 * D + lane * 4);
        acc.x += v0.x; acc.y += v0.y; acc.z += v0.z; acc.w += v0.w;
        acc.x += v1.x; acc.y += v1.y; acc.z += v1.z; acc.w += v1.w;
    }
    if (j < cnt) {
        int s0 = csr_src[beg + j];
        float4 v0 = *reinterpret_cast<const float4*>(feature + (size_t)s0 * D + lane * 4);
        acc.x += v0.x; acc.y += v0.y; acc.z += v0.z; acc.w += v0.w;
    }
    *reinterpret_cast<float4*>(agg + (size_t)node * D + lane * 4) = acc;
}

// ---------------------------------------------------------------------------
// Fallback (ws too small): direct atomic scatter.
// ---------------------------------------------------------------------------
__global__ __launch_bounds__(256) void scatter_kernel(
    const float* __restrict__ feature,
    const int* __restrict__ src,
    const int* __restrict__ dst,
    float* __restrict__ agg, int E)
{
    int edge = blockIdx.x * (blockDim.x >> 6) + (threadIdx.x >> 6);
    int lane = threadIdx.x & 63;
    if (edge >= E) return;
    int s = src[edge];
    int d = dst[edge];
    const float4 v = *reinterpret_cast<const float4*>(feature + (size_t)s * D + lane * 4);
    float* o = agg + (size_t)d * D + lane * 4;
    atomicAdd(o + 0, v.x);
    atomicAdd(o + 1, v.y);
    atomicAdd(o + 2, v.z);
    atomicAdd(o + 3, v.w);
}

// ---------------------------------------------------------------------------
// In-place per-row Linear + ReLU (unchanged from round 1).
// ---------------------------------------------------------------------------
#define BM 32

__global__ __launch_bounds__(256) void linear_relu_kernel(
    float* __restrict__ h, const float* __restrict__ W,
    const float* __restrict__ b, int n_nodes)
{
    __shared__ float sA[BM][D];
    const int node0 = blockIdx.x * BM;
    const int t = threadIdx.x;

    for (int m = 0; m < BM; ++m) {
        int nd = node0 + m;
        sA[m][t] = (nd < n_nodes) ? h[(size_t)nd * D + t] : 0.0f;
    }
    __syncthreads();

    float acc[BM];
#pragma unroll
    for (int m = 0; m < BM; ++m) acc[m] = 0.0f;

    for (int k = 0; k < D; ++k) {
        float w = W[k * D + t];
#pragma unroll
        for (int m = 0; m < BM; ++m) acc[m] += sA[m][k] * w;
    }

    const float bias = b[t];
    for (int m = 0; m < BM; ++m) {
        int nd = node0 + m;
        if (nd < n_nodes) {
            float v = acc[m] + bias;
            h[(size_t)nd * D + t] = v > 0.0f ? v : 0.0f;
        }
    }
}

// ---------------------------------------------------------------------------
extern "C" void kernel_launch(void* const* d_in, const int* in_sizes, int n_in,
                              void* d_out, int out_size, void* d_ws, size_t ws_size,
                              hipStream_t stream)
{
    const float* feature = (const float*)d_in[0];
    const int*   src     = (const int*)d_in[1];
    const int*   dst     = (const int*)d_in[2];
    const float* W       = (const float*)d_in[3];
    const float* b       = (const float*)d_in[4];
    float*       out     = (float*)d_out;

    const int E = in_sizes[1];
    const int N = in_sizes[0] / D;

    // workspace layout: counts[N] | offsets[N+1] | cursor[N] | csr_src[E]
    const size_t need = ((size_t)N + (size_t)(N + 1) + (size_t)N + (size_t)E) * sizeof(int);

    if (ws_size >= need) {
        int* counts  = (int*)d_ws;
        int* offsets = counts + N;
        int* cursor  = offsets + (N + 1);
        int* csr_src = cursor + N;

        hipMemsetAsync(counts, 0, (size_t)N * sizeof(int), stream);

        count_kernel<<<1024, 256, 0, stream>>>(dst, counts, E);
        scan_kernel<<<1, 1024, 0, stream>>>(counts, offsets, cursor, N);
        build_kernel<<<1024, 256, 0, stream>>>(src, dst, cursor, csr_src, E);

        int grid = (N + 3) / 4;   // 4 nodes (waves) per 256-thread block
        aggregate_kernel<<<grid, 256, 0, stream>>>(feature, csr_src, offsets, counts, out, N);
    } else {
        hipMemsetAsync(d_out, 0, (size_t)out_size * sizeof(float), stream);
        int grid = (E + 3) / 4;
        scatter_kernel<<<grid, 256, 0, stream>>>(feature, src, dst, out, E);
    }

    // in-place linear + relu
    {
        int grid = (N + BM - 1) / BM;
        linear_relu_kernel<<<grid, 256, 0, stream>>>(out, W, b, N);
    }
}

// Round 3
// 1043.639 us; speedup vs baseline: 10.5841x; 1.4434x over previous
//
#include <hip/hip_runtime.h>

#define D 256

using bf16x8 = __attribute__((ext_vector_type(8))) short;
using f32x4  = __attribute__((ext_vector_type(4))) float;

__device__ inline float bf_lo(unsigned int u) {
    return __builtin_bit_cast(float, u << 16);
}
__device__ inline float bf_hi(unsigned int u) {
    return __builtin_bit_cast(float, u & 0xffff0000u);
}
__device__ inline unsigned short f2bf(float f) {
    unsigned int x = __builtin_bit_cast(unsigned int, f);
    unsigned int r = (x + 0x7fffu + ((x >> 16) & 1u)) >> 16;   // RNE
    return (unsigned short)r;
}

// ---------------------------------------------------------------------------
// Converters
// ---------------------------------------------------------------------------
__global__ __launch_bounds__(256) void conv_feature_kernel(
    const float* __restrict__ f, unsigned short* __restrict__ o, long n8)
{
    long i = (long)blockIdx.x * blockDim.x + threadIdx.x;   // 8 floats each
    if (i >= n8) return;
    const float4* p = reinterpret_cast<const float4*>(f + i * 8);
    float4 v0 = p[0], v1 = p[1];
    uint4 r;
    r.x = (unsigned int)f2bf(v0.x) | ((unsigned int)f2bf(v0.y) << 16);
    r.y = (unsigned int)f2bf(v0.z) | ((unsigned int)f2bf(v0.w) << 16);
    r.z = (unsigned int)f2bf(v1.x) | ((unsigned int)f2bf(v1.y) << 16);
    r.w = (unsigned int)f2bf(v1.z) | ((unsigned int)f2bf(v1.w) << 16);
    *reinterpret_cast<uint4*>(o + i * 8) = r;
}

// Wt[n][k] = bf16(W[k][n])
__global__ __launch_bounds__(256) void conv_w_kernel(
    const float* __restrict__ W, unsigned short* __restrict__ Wt)
{
    int i = blockIdx.x * blockDim.x + threadIdx.x;   // 4 k's each
    if (i >= D * D / 4) return;
    int n  = i >> 6;
    int k0 = (i & 63) * 4;
    float a = W[(size_t)(k0 + 0) * D + n];
    float b = W[(size_t)(k0 + 1) * D + n];
    float c = W[(size_t)(k0 + 2) * D + n];
    float d = W[(size_t)(k0 + 3) * D + n];
    uint2 r;
    r.x = (unsigned int)f2bf(a) | ((unsigned int)f2bf(b) << 16);
    r.y = (unsigned int)f2bf(c) | ((unsigned int)f2bf(d) << 16);
    *reinterpret_cast<uint2*>(Wt + (size_t)n * D + k0) = r;
}

// ---------------------------------------------------------------------------
// CSR build: counting sort of edges by dst.
// ---------------------------------------------------------------------------
__global__ __launch_bounds__(256) void count_kernel(
    const int* __restrict__ dst, int* __restrict__ counts, int E)
{
    int i = blockIdx.x * blockDim.x + threadIdx.x;
    int stride = gridDim.x * blockDim.x;
    for (; i < E; i += stride) atomicAdd(&counts[dst[i]], 1);
}

__global__ __launch_bounds__(1024) void scan_kernel(
    const int* __restrict__ counts, int* __restrict__ offsets,
    int* __restrict__ cursor, int N)
{
    __shared__ int sm[1024];
    const int t = threadIdx.x;
    const int chunk = (N + 1023) / 1024;
    const int begin = min(t * chunk, N);
    const int end   = min(begin + chunk, N);

    int s = 0;
    for (int i = begin; i < end; ++i) s += counts[i];
    sm[t] = s;
    __syncthreads();

    for (int off = 1; off < 1024; off <<= 1) {
        int v = (t >= off) ? sm[t - off] : 0;
        __syncthreads();
        if (t >= off) sm[t] += v;
        __syncthreads();
    }

    int run = (t == 0) ? 0 : sm[t - 1];
    for (int i = begin; i < end; ++i) {
        offsets[i] = run;
        cursor[i]  = run;
        run += counts[i];
    }
    if (end == N && begin < N) offsets[N] = run;
}

__global__ __launch_bounds__(256) void build_kernel(
    const int* __restrict__ src, const int* __restrict__ dst,
    int* __restrict__ cursor, int* __restrict__ csr_src, int E)
{
    int i = blockIdx.x * blockDim.x + threadIdx.x;
    int stride = gridDim.x * blockDim.x;
    for (; i < E; i += stride) {
        int d = dst[i];
        int p = atomicAdd(&cursor[d], 1);
        csr_src[p] = src[i];
    }
}

// ---------------------------------------------------------------------------
// Aggregate (bf16 in, bf16 out, fp32 accumulate).
// One wave per node; lane owns 4 consecutive columns (uint2 = 4 bf16).
// ---------------------------------------------------------------------------
__global__ __launch_bounds__(256) void aggregate_bf16_kernel(
    const unsigned short* __restrict__ fbf,
    const int* __restrict__ csr_src,
    const int* __restrict__ offsets,
    const int* __restrict__ counts,
    unsigned short* __restrict__ aggb, int N)
{
    int node = blockIdx.x * 4 + (threadIdx.x >> 6);
    int lane = threadIdx.x & 63;
    if (node >= N) return;

    const int beg = offsets[node];
    const int cnt = counts[node];
    const int col = lane * 4;

    float a0 = 0.f, a1 = 0.f, a2 = 0.f, a3 = 0.f;
    int j = 0;
    for (; j + 1 < cnt; j += 2) {
        int s0 = csr_src[beg + j];
        int s1 = csr_src[beg + j + 1];
        uint2 v0 = *reinterpret_cast<const uint2*>(fbf + (size_t)s0 * D + col);
        uint2 v1 = *reinterpret_cast<const uint2*>(fbf + (size_t)s1 * D + col);
        a0 += bf_lo(v0.x); a1 += bf_hi(v0.x); a2 += bf_lo(v0.y); a3 += bf_hi(v0.y);
        a0 += bf_lo(v1.x); a1 += bf_hi(v1.x); a2 += bf_lo(v1.y); a3 += bf_hi(v1.y);
    }
    if (j < cnt) {
        int s0 = csr_src[beg + j];
        uint2 v0 = *reinterpret_cast<const uint2*>(fbf + (size_t)s0 * D + col);
        a0 += bf_lo(v0.x); a1 += bf_hi(v0.x); a2 += bf_lo(v0.y); a3 += bf_hi(v0.y);
    }
    uint2 r;
    r.x = (unsigned int)f2bf(a0) | ((unsigned int)f2bf(a1) << 16);
    r.y = (unsigned int)f2bf(a2) | ((unsigned int)f2bf(a3) << 16);
    *reinterpret_cast<uint2*>(aggb + (size_t)node * D + col) = r;
}

// ---------------------------------------------------------------------------
// MFMA GEMM: out[M][256] = relu(aggb[M][256] @ W + b), W given as Wt[n][k].
// One wave per 16 rows. A fragments held in registers (16x256 bf16 = 32 VGPR).
// mfma_f32_16x16x32_bf16: A frag lane l: row=l&15, k=(l>>4)*8+j;
//                         B frag lane l: col=l&15, k=(l>>4)*8+j;
//                         D      lane l: col=l&15, row=(l>>4)*4+reg.
// ---------------------------------------------------------------------------
__global__ __launch_bounds__(256) void gemm_kernel(
    const unsigned short* __restrict__ A,    // [M][256] bf16
    const unsigned short* __restrict__ Wt,   // [256][256] bf16, Wt[n][k]
    const float* __restrict__ bias,
    float* __restrict__ out, int M)
{
    const int wave = threadIdx.x >> 6;
    const int lane = threadIdx.x & 63;
    const int row0 = (blockIdx.x * 4 + wave) * 16;
    if (row0 >= M) return;

    const int lr = lane & 15;
    const int lg = lane >> 4;

    bf16x8 a[8];
    const unsigned short* ap = A + (size_t)(row0 + lr) * D + lg * 8;
#pragma unroll
    for (int ks = 0; ks < 8; ++ks)
        a[ks] = *reinterpret_cast<const bf16x8*>(ap + ks * 32);

    for (int ct = 0; ct < 16; ++ct) {
        f32x4 acc = {0.f, 0.f, 0.f, 0.f};
        const unsigned short* bp = Wt + (size_t)(ct * 16 + lr) * D + lg * 8;
#pragma unroll
        for (int ks = 0; ks < 8; ++ks) {
            bf16x8 bfr = *reinterpret_cast<const bf16x8*>(bp + ks * 32);
            acc = __builtin_amdgcn_mfma_f32_16x16x32_bf16(a[ks], bfr, acc, 0, 0, 0);
        }
        const float bv = bias[ct * 16 + lr];
#pragma unroll
        for (int j = 0; j < 4; ++j) {
            float v = acc[j] + bv;
            out[(size_t)(row0 + lg * 4 + j) * D + ct * 16 + lr] = v > 0.f ? v : 0.f;
        }
    }
}

// ---------------------------------------------------------------------------
// fp32 fallback kernels (round-2 path, used only if ws is too small)
// ---------------------------------------------------------------------------
__global__ __launch_bounds__(256) void aggregate_kernel(
    const float* __restrict__ feature, const int* __restrict__ csr_src,
    const int* __restrict__ offsets, const int* __restrict__ counts,
    float* __restrict__ agg, int N)
{
    int node = blockIdx.x * 4 + (threadIdx.x >> 6);
    int lane = threadIdx.x & 63;
    if (node >= N) return;
    const int beg = offsets[node];
    const int cnt = counts[node];
    float4 acc = make_float4(0.f, 0.f, 0.f, 0.f);
    for (int j = 0; j < cnt; ++j) {
        int s0 = csr_src[beg + j];
        float4 v0 = *reinterpret_cast<const float4*>(feature + (size_t)s0 * D + lane * 4);
        acc.x += v0.x; acc.y += v0.y; acc.z += v0.z; acc.w += v0.w;
    }
    *reinterpret_cast<float4*>(agg + (size_t)node * D + lane * 4) = acc;
}

__global__ __launch_bounds__(256) void scatter_kernel(
    const float* __restrict__ feature, const int* __restrict__ src,
    const int* __restrict__ dst, float* __restrict__ agg, int E)
{
    int edge = blockIdx.x * (blockDim.x >> 6) + (threadIdx.x >> 6);
    int lane = threadIdx.x & 63;
    if (edge >= E) return;
    int s = src[edge];
    int d = dst[edge];
    const float4 v = *reinterpret_cast<const float4*>(feature + (size_t)s * D + lane * 4);
    float* o = agg + (size_t)d * D + lane * 4;
    atomicAdd(o + 0, v.x);
    atomicAdd(o + 1, v.y);
    atomicAdd(o + 2, v.z);
    atomicAdd(o + 3, v.w);
}

#define BM 32
__global__ __launch_bounds__(256) void linear_relu_kernel(
    float* __restrict__ h, const float* __restrict__ W,
    const float* __restrict__ b, int n_nodes)
{
    __shared__ float sA[BM][D];
    const int node0 = blockIdx.x * BM;
    const int t = threadIdx.x;
    for (int m = 0; m < BM; ++m) {
        int nd = node0 + m;
        sA[m][t] = (nd < n_nodes) ? h[(size_t)nd * D + t] : 0.0f;
    }
    __syncthreads();
    float acc[BM];
#pragma unroll
    for (int m = 0; m < BM; ++m) acc[m] = 0.0f;
    for (int k = 0; k < D; ++k) {
        float w = W[k * D + t];
#pragma unroll
        for (int m = 0; m < BM; ++m) acc[m] += sA[m][k] * w;
    }
    const float bias = b[t];
    for (int m = 0; m < BM; ++m) {
        int nd = node0 + m;
        if (nd < n_nodes) {
            float v = acc[m] + bias;
            h[(size_t)nd * D + t] = v > 0.0f ? v : 0.0f;
        }
    }
}

// ---------------------------------------------------------------------------
extern "C" void kernel_launch(void* const* d_in, const int* in_sizes, int n_in,
                              void* d_out, int out_size, void* d_ws, size_t ws_size,
                              hipStream_t stream)
{
    const float* feature = (const float*)d_in[0];
    const int*   src     = (const int*)d_in[1];
    const int*   dst     = (const int*)d_in[2];
    const float* W       = (const float*)d_in[3];
    const float* b       = (const float*)d_in[4];
    float*       out     = (float*)d_out;

    const int E = in_sizes[1];
    const int N = in_sizes[0] / D;

    // ---- workspace layout -------------------------------------------------
    size_t off = 0;
    auto alloc = [&](size_t bytes, size_t align) {
        off = (off + align - 1) / align * align;
        size_t r = off; off += bytes; return r;
    };
    size_t o_counts  = alloc((size_t)N * 4, 4);
    size_t o_offsets = alloc((size_t)(N + 1) * 4, 4);
    size_t o_cursor  = alloc((size_t)N * 4, 4);
    size_t o_csr     = alloc((size_t)E * 4, 4);
    size_t need_csr  = off;
    size_t o_wt      = alloc((size_t)D * D * 2, 16);
    size_t o_fbf     = alloc((size_t)N * D * 2, 16);
    size_t o_aggb    = alloc((size_t)N * D * 2, 16);
    size_t need_full = off;

    char* ws = (char*)d_ws;

    if (ws_size >= need_full) {
        int* counts  = (int*)(ws + o_counts);
        int* offsets = (int*)(ws + o_offsets);
        int* cursor  = (int*)(ws + o_cursor);
        int* csr_src = (int*)(ws + o_csr);
        unsigned short* Wt   = (unsigned short*)(ws + o_wt);
        unsigned short* fbf  = (unsigned short*)(ws + o_fbf);
        unsigned short* aggb = (unsigned short*)(ws + o_aggb);

        hipMemsetAsync(counts, 0, (size_t)N * 4, stream);

        {   // feature -> bf16 (8 floats per thread)
            long n8 = (long)N * D / 8;
            int grid = (int)((n8 + 255) / 256);
            conv_feature_kernel<<<grid, 256, 0, stream>>>(feature, fbf, n8);
        }
        conv_w_kernel<<<(D * D / 4 + 255) / 256, 256, 0, stream>>>(W, Wt);

        count_kernel<<<1024, 256, 0, stream>>>(dst, counts, E);
        scan_kernel<<<1, 1024, 0, stream>>>(counts, offsets, cursor, N);
        build_kernel<<<1024, 256, 0, stream>>>(src, dst, cursor, csr_src, E);

        aggregate_bf16_kernel<<<(N + 3) / 4, 256, 0, stream>>>(
            fbf, csr_src, offsets, counts, aggb, N);

        gemm_kernel<<<(N + 63) / 64, 256, 0, stream>>>(aggb, Wt, b, out, N);
    } else if (ws_size >= need_csr) {
        int* counts  = (int*)(ws + o_counts);
        int* offsets = (int*)(ws + o_offsets);
        int* cursor  = (int*)(ws + o_cursor);
        int* csr_src = (int*)(ws + o_csr);

        hipMemsetAsync(counts, 0, (size_t)N * 4, stream);
        count_kernel<<<1024, 256, 0, stream>>>(dst, counts, E);
        scan_kernel<<<1, 1024, 0, stream>>>(counts, offsets, cursor, N);
        build_kernel<<<1024, 256, 0, stream>>>(src, dst, cursor, csr_src, E);
        aggregate_kernel<<<(N + 3) / 4, 256, 0, stream>>>(
            feature, csr_src, offsets, counts, out, N);
        linear_relu_kernel<<<(N + BM - 1) / BM, 256, 0, stream>>>(out, W, b, N);
    } else {
        hipMemsetAsync(d_out, 0, (size_t)out_size * sizeof(float), stream);
        scatter_kernel<<<(E + 3) / 4, 256, 0, stream>>>(feature, src, dst, out, E);
        linear_relu_kernel<<<(N + BM - 1) / BM, 256, 0, stream>>>(out, W, b, N);
    }
}

// Round 4
// 634.665 us; speedup vs baseline: 17.4045x; 1.6444x over previous
//
#include <hip/hip_runtime.h>

#define D 256
#define BSHIFT 6
#define BSIZE 64          // nodes per bucket
#define KMAX 2048         // max buckets supported by LDS hist
#define NB_P 512          // partition blocks

using bf16x8 = __attribute__((ext_vector_type(8))) short;
using f32x4  = __attribute__((ext_vector_type(4))) float;

__device__ inline float bf_lo(unsigned int u) {
    return __builtin_bit_cast(float, u << 16);
}
__device__ inline float bf_hi(unsigned int u) {
    return __builtin_bit_cast(float, u & 0xffff0000u);
}
__device__ inline unsigned short f2bf(float f) {
    unsigned int x = __builtin_bit_cast(unsigned int, f);
    unsigned int r = (x + 0x7fffu + ((x >> 16) & 1u)) >> 16;   // RNE
    return (unsigned short)r;
}

// ---------------------------------------------------------------------------
// Converters
// ---------------------------------------------------------------------------
__global__ __launch_bounds__(256) void conv_feature_kernel(
    const float* __restrict__ f, unsigned short* __restrict__ o, long n8)
{
    long i = (long)blockIdx.x * blockDim.x + threadIdx.x;   // 8 floats each
    if (i >= n8) return;
    const float4* p = reinterpret_cast<const float4*>(f + i * 8);
    float4 v0 = p[0], v1 = p[1];
    uint4 r;
    r.x = (unsigned int)f2bf(v0.x) | ((unsigned int)f2bf(v0.y) << 16);
    r.y = (unsigned int)f2bf(v0.z) | ((unsigned int)f2bf(v0.w) << 16);
    r.z = (unsigned int)f2bf(v1.x) | ((unsigned int)f2bf(v1.y) << 16);
    r.w = (unsigned int)f2bf(v1.z) | ((unsigned int)f2bf(v1.w) << 16);
    *reinterpret_cast<uint4*>(o + i * 8) = r;
}

// Wt[n][k] = bf16(W[k][n])
__global__ __launch_bounds__(256) void conv_w_kernel(
    const float* __restrict__ W, unsigned short* __restrict__ Wt)
{
    int i = blockIdx.x * blockDim.x + threadIdx.x;   // 4 k's each
    if (i >= D * D / 4) return;
    int n  = i >> 6;
    int k0 = (i & 63) * 4;
    float a = W[(size_t)(k0 + 0) * D + n];
    float b = W[(size_t)(k0 + 1) * D + n];
    float c = W[(size_t)(k0 + 2) * D + n];
    float d = W[(size_t)(k0 + 3) * D + n];
    uint2 r;
    r.x = (unsigned int)f2bf(a) | ((unsigned int)f2bf(b) << 16);
    r.y = (unsigned int)f2bf(c) | ((unsigned int)f2bf(d) << 16);
    *reinterpret_cast<uint2*>(Wt + (size_t)n * D + k0) = r;
}

// ---------------------------------------------------------------------------
// Atomic-free CSR build: per-block-histogram radix partition by dst>>6,
// then per-bucket LDS counting sort.
// ---------------------------------------------------------------------------
__global__ __launch_bounds__(256) void histA_kernel(
    const int* __restrict__ dst, int* __restrict__ blockHist,
    int E, int K, int chunk)
{
    __shared__ int h[KMAX];
    const int b = blockIdx.x, t = threadIdx.x;
    for (int i = t; i < K; i += 256) h[i] = 0;
    __syncthreads();
    const int beg = b * chunk;
    const int end = min(beg + chunk, E);
    for (int i = beg + t; i < end; i += 256)
        atomicAdd(&h[dst[i] >> BSHIFT], 1);
    __syncthreads();
    for (int i = t; i < K; i += 256)
        blockHist[(size_t)b * K + i] = h[i];
}

// Column-wise exclusive scan: blockHist[b][k] -> prefix over b; totals[k] = col sum.
__global__ __launch_bounds__(256) void colscan_kernel(
    int* __restrict__ blockHist, int* __restrict__ totals, int K, int NB)
{
    int k = blockIdx.x * 256 + threadIdx.x;
    if (k >= K) return;
    int run = 0;
    for (int b = 0; b < NB; ++b) {
        size_t idx = (size_t)b * K + k;
        int v = blockHist[idx];
        blockHist[idx] = run;
        run += v;
    }
    totals[k] = run;
}

// Single-block exclusive scan over K bucket totals -> base[0..K].
__global__ __launch_bounds__(1024) void basescan_kernel(
    const int* __restrict__ totals, int* __restrict__ base, int K)
{
    __shared__ int sm[1024];
    const int t = threadIdx.x;
    const int chunk = (K + 1023) / 1024;
    const int b0 = min(t * chunk, K);
    const int e0 = min(b0 + chunk, K);
    int s = 0;
    for (int i = b0; i < e0; ++i) s += totals[i];
    sm[t] = s;
    __syncthreads();
    for (int off = 1; off < 1024; off <<= 1) {
        int v = (t >= off) ? sm[t - off] : 0;
        __syncthreads();
        if (t >= off) sm[t] += v;
        __syncthreads();
    }
    int run = (t == 0) ? 0 : sm[t - 1];
    for (int i = b0; i < e0; ++i) { base[i] = run; run += totals[i]; }
    if (e0 == K && b0 < K) base[K] = run;
}

// Scatter edges into bucket-partitioned order; packed = (src<<6)|dstLocal.
__global__ __launch_bounds__(256) void scatterB_kernel(
    const int* __restrict__ src, const int* __restrict__ dst,
    const int* __restrict__ blockHist, const int* __restrict__ base,
    int* __restrict__ csrPacked, int E, int K, int chunk)
{
    __shared__ int cur[KMAX];
    const int b = blockIdx.x, t = threadIdx.x;
    for (int i = t; i < K; i += 256)
        cur[i] = blockHist[(size_t)b * K + i] + base[i];
    __syncthreads();
    const int beg = b * chunk;
    const int end = min(beg + chunk, E);
    for (int i = beg + t; i < end; i += 256) {
        int d = dst[i], s = src[i];
        int k = d >> BSHIFT;
        int r = atomicAdd(&cur[k], 1);    // LDS atomic
        csrPacked[r] = (s << BSHIFT) | (d & (BSIZE - 1));
    }
}

// Per-bucket counting sort over 64 local nodes -> csr_src, offsets, counts.
__global__ __launch_bounds__(256) void sortC_kernel(
    const int* __restrict__ csrPacked, const int* __restrict__ base,
    int* __restrict__ csr_src, int* __restrict__ offsets,
    int* __restrict__ counts, int N)
{
    __shared__ int hist[BSIZE];
    __shared__ int pref[BSIZE];
    __shared__ int cur[BSIZE];
    const int k = blockIdx.x, t = threadIdx.x;
    const int beg = base[k], end = base[k + 1];

    if (t < BSIZE) hist[t] = 0;
    __syncthreads();
    for (int i = beg + t; i < end; i += 256)
        atomicAdd(&hist[csrPacked[i] & (BSIZE - 1)], 1);
    __syncthreads();
    if (t == 0) {
        int run = 0;
        for (int j = 0; j < BSIZE; ++j) { pref[j] = run; run += hist[j]; }
    }
    __syncthreads();
    if (t < BSIZE) {
        cur[t] = pref[t];
        int node = (k << BSHIFT) + t;
        if (node < N) {
            offsets[node] = beg + pref[t];
            counts[node]  = hist[t];
        }
    }
    __syncthreads();
    for (int i = beg + t; i < end; i += 256) {
        int p = csrPacked[i];
        int r = atomicAdd(&cur[p & (BSIZE - 1)], 1);   // LDS atomic
        csr_src[beg + r] = p >> BSHIFT;
    }
}

// ---------------------------------------------------------------------------
// Aggregate: bf16 gather, fp32 accumulate, fp32 write (direct to d_out).
// One wave per node; lane owns 4 consecutive columns.
// ---------------------------------------------------------------------------
__global__ __launch_bounds__(256) void aggregate_kernel(
    const unsigned short* __restrict__ fbf,
    const int* __restrict__ csr_src,
    const int* __restrict__ offsets,
    const int* __restrict__ counts,
    float* __restrict__ agg, int N)
{
    int node = blockIdx.x * 4 + (threadIdx.x >> 6);
    int lane = threadIdx.x & 63;
    if (node >= N) return;

    const int beg = offsets[node];
    const int cnt = counts[node];
    const int col = lane * 4;

    float a0 = 0.f, a1 = 0.f, a2 = 0.f, a3 = 0.f;
    int j = 0;
    for (; j + 3 < cnt; j += 4) {
        int s0 = csr_src[beg + j];
        int s1 = csr_src[beg + j + 1];
        int s2 = csr_src[beg + j + 2];
        int s3 = csr_src[beg + j + 3];
        uint2 v0 = *reinterpret_cast<const uint2*>(fbf + (size_t)s0 * D + col);
        uint2 v1 = *reinterpret_cast<const uint2*>(fbf + (size_t)s1 * D + col);
        uint2 v2 = *reinterpret_cast<const uint2*>(fbf + (size_t)s2 * D + col);
        uint2 v3 = *reinterpret_cast<const uint2*>(fbf + (size_t)s3 * D + col);
        a0 += bf_lo(v0.x); a1 += bf_hi(v0.x); a2 += bf_lo(v0.y); a3 += bf_hi(v0.y);
        a0 += bf_lo(v1.x); a1 += bf_hi(v1.x); a2 += bf_lo(v1.y); a3 += bf_hi(v1.y);
        a0 += bf_lo(v2.x); a1 += bf_hi(v2.x); a2 += bf_lo(v2.y); a3 += bf_hi(v2.y);
        a0 += bf_lo(v3.x); a1 += bf_hi(v3.x); a2 += bf_lo(v3.y); a3 += bf_hi(v3.y);
    }
    for (; j < cnt; ++j) {
        int s0 = csr_src[beg + j];
        uint2 v0 = *reinterpret_cast<const uint2*>(fbf + (size_t)s0 * D + col);
        a0 += bf_lo(v0.x); a1 += bf_hi(v0.x); a2 += bf_lo(v0.y); a3 += bf_hi(v0.y);
    }
    float4 r = make_float4(a0, a1, a2, a3);
    *reinterpret_cast<float4*>(agg + (size_t)node * D + col) = r;
}

// ---------------------------------------------------------------------------
// In-place MFMA GEMM: h[M][256] = relu(h[M][256] @ W + b), W as Wt[n][k] bf16.
// One wave per 16 rows; each wave reads ALL its A data before storing, and
// waves own disjoint row sets -> in-place is safe. `h` deliberately not
// __restrict__ (it aliases itself) so stores can't be hoisted above loads.
// ---------------------------------------------------------------------------
__global__ __launch_bounds__(256) void gemm_kernel(
    float* h,
    const unsigned short* __restrict__ Wt,
    const float* __restrict__ bias, int M)
{
    const int wave = threadIdx.x >> 6;
    const int lane = threadIdx.x & 63;
    const int row0 = (blockIdx.x * 4 + wave) * 16;
    if (row0 >= M) return;

    const int lr = lane & 15;
    const int lg = lane >> 4;

    const int rowA = min(row0 + lr, M - 1);
    const float* ap = h + (size_t)rowA * D + lg * 8;

    bf16x8 a[8];
#pragma unroll
    for (int ks = 0; ks < 8; ++ks) {
        float4 v0 = *reinterpret_cast<const float4*>(ap + ks * 32);
        float4 v1 = *reinterpret_cast<const float4*>(ap + ks * 32 + 4);
        bf16x8 f;
        f[0] = (short)f2bf(v0.x); f[1] = (short)f2bf(v0.y);
        f[2] = (short)f2bf(v0.z); f[3] = (short)f2bf(v0.w);
        f[4] = (short)f2bf(v1.x); f[5] = (short)f2bf(v1.y);
        f[6] = (short)f2bf(v1.z); f[7] = (short)f2bf(v1.w);
        a[ks] = f;
    }

    for (int ct = 0; ct < 16; ++ct) {
        f32x4 acc = {0.f, 0.f, 0.f, 0.f};
        const unsigned short* bp = Wt + (size_t)(ct * 16 + lr) * D + lg * 8;
#pragma unroll
        for (int ks = 0; ks < 8; ++ks) {
            bf16x8 bfr = *reinterpret_cast<const bf16x8*>(bp + ks * 32);
            acc = __builtin_amdgcn_mfma_f32_16x16x32_bf16(a[ks], bfr, acc, 0, 0, 0);
        }
        const float bv = bias[ct * 16 + lr];
#pragma unroll
        for (int jj = 0; jj < 4; ++jj) {
            int row = row0 + lg * 4 + jj;
            if (row < M) {
                float v = acc[jj] + bv;
                h[(size_t)row * D + ct * 16 + lr] = v > 0.f ? v : 0.f;
            }
        }
    }
}

// ---------------------------------------------------------------------------
// Fallback kernels (ws too small): direct atomic scatter + VALU linear.
// ---------------------------------------------------------------------------
__global__ __launch_bounds__(256) void scatter_kernel(
    const float* __restrict__ feature, const int* __restrict__ src,
    const int* __restrict__ dst, float* __restrict__ agg, int E)
{
    int edge = blockIdx.x * (blockDim.x >> 6) + (threadIdx.x >> 6);
    int lane = threadIdx.x & 63;
    if (edge >= E) return;
    int s = src[edge];
    int d = dst[edge];
    const float4 v = *reinterpret_cast<const float4*>(feature + (size_t)s * D + lane * 4);
    float* o = agg + (size_t)d * D + lane * 4;
    atomicAdd(o + 0, v.x);
    atomicAdd(o + 1, v.y);
    atomicAdd(o + 2, v.z);
    atomicAdd(o + 3, v.w);
}

#define BM 32
__global__ __launch_bounds__(256) void linear_relu_kernel(
    float* __restrict__ h, const float* __restrict__ W,
    const float* __restrict__ b, int n_nodes)
{
    __shared__ float sA[BM][D];
    const int node0 = blockIdx.x * BM;
    const int t = threadIdx.x;
    for (int m = 0; m < BM; ++m) {
        int nd = node0 + m;
        sA[m][t] = (nd < n_nodes) ? h[(size_t)nd * D + t] : 0.0f;
    }
    __syncthreads();
    float acc[BM];
#pragma unroll
    for (int m = 0; m < BM; ++m) acc[m] = 0.0f;
    for (int k = 0; k < D; ++k) {
        float w = W[k * D + t];
#pragma unroll
        for (int m = 0; m < BM; ++m) acc[m] += sA[m][k] * w;
    }
    const float bias = b[t];
    for (int m = 0; m < BM; ++m) {
        int nd = node0 + m;
        if (nd < n_nodes) {
            float v = acc[m] + bias;
            h[(size_t)nd * D + t] = v > 0.0f ? v : 0.0f;
        }
    }
}

// ---------------------------------------------------------------------------
extern "C" void kernel_launch(void* const* d_in, const int* in_sizes, int n_in,
                              void* d_out, int out_size, void* d_ws, size_t ws_size,
                              hipStream_t stream)
{
    const float* feature = (const float*)d_in[0];
    const int*   src     = (const int*)d_in[1];
    const int*   dst     = (const int*)d_in[2];
    const float* W       = (const float*)d_in[3];
    const float* b       = (const float*)d_in[4];
    float*       out     = (float*)d_out;

    const int E = in_sizes[1];
    const int N = in_sizes[0] / D;
    const int K = (N + BSIZE - 1) >> BSHIFT;        // buckets
    const int chunk = (E + NB_P - 1) / NB_P;

    // ---- workspace layout -------------------------------------------------
    size_t off = 0;
    auto alloc = [&](size_t bytes, size_t align) {
        off = (off + align - 1) / align * align;
        size_t r = off; off += bytes; return r;
    };
    size_t o_bh     = alloc((size_t)NB_P * K * 4, 16);
    size_t o_tot    = alloc((size_t)K * 4, 16);
    size_t o_base   = alloc((size_t)(K + 1) * 4, 16);
    size_t o_packed = alloc((size_t)E * 4, 16);
    size_t o_csr    = alloc((size_t)E * 4, 16);
    size_t o_off    = alloc((size_t)N * 4, 16);
    size_t o_cnt    = alloc((size_t)N * 4, 16);
    size_t o_wt     = alloc((size_t)D * D * 2, 16);
    size_t o_fbf    = alloc((size_t)N * D * 2, 16);
    size_t need_full = off;

    char* ws = (char*)d_ws;

    if (ws_size >= need_full && K <= KMAX) {
        int* blockHist = (int*)(ws + o_bh);
        int* totals    = (int*)(ws + o_tot);
        int* base      = (int*)(ws + o_base);
        int* csrPacked = (int*)(ws + o_packed);
        int* csr_src   = (int*)(ws + o_csr);
        int* offsets   = (int*)(ws + o_off);
        int* counts    = (int*)(ws + o_cnt);
        unsigned short* Wt  = (unsigned short*)(ws + o_wt);
        unsigned short* fbf = (unsigned short*)(ws + o_fbf);

        {   // feature -> bf16
            long n8 = (long)N * D / 8;
            conv_feature_kernel<<<(int)((n8 + 255) / 256), 256, 0, stream>>>(
                feature, fbf, n8);
        }
        conv_w_kernel<<<(D * D / 4 + 255) / 256, 256, 0, stream>>>(W, Wt);

        histA_kernel<<<NB_P, 256, 0, stream>>>(dst, blockHist, E, K, chunk);
        colscan_kernel<<<(K + 255) / 256, 256, 0, stream>>>(blockHist, totals, K, NB_P);
        basescan_kernel<<<1, 1024, 0, stream>>>(totals, base, K);
        scatterB_kernel<<<NB_P, 256, 0, stream>>>(
            src, dst, blockHist, base, csrPacked, E, K, chunk);
        sortC_kernel<<<K, 256, 0, stream>>>(
            csrPacked, base, csr_src, offsets, counts, N);

        aggregate_kernel<<<(N + 3) / 4, 256, 0, stream>>>(
            fbf, csr_src, offsets, counts, out, N);

        gemm_kernel<<<(N + 63) / 64, 256, 0, stream>>>(out, Wt, b, N);
    } else {
        hipMemsetAsync(d_out, 0, (size_t)out_size * sizeof(float), stream);
        scatter_kernel<<<(E + 3) / 4, 256, 0, stream>>>(feature, src, dst, out, E);
        linear_relu_kernel<<<(N + BM - 1) / BM, 256, 0, stream>>>(out, W, b, N);
    }
}